// Round 1
// baseline (1392.354 us; speedup 1.0000x reference)
//
#include <hip/hip_runtime.h>
#include <math.h>

// Problem constants (fixed by reference)
#define ATT   16
#define SKK   3
#define LKK   13
#define CIN   64
#define HID   8
#define BB    16
#define HH    192
#define WW    192
#define HALO  6          // LK//2
#define TH    8
#define TW    32
#define TILE_H (TH + 2*HALO)   // 20
#define TILE_W (TW + 2*HALO)   // 44
#define NIDT  (CIN - ATT)      // 48

// ---------------- Kernel 1: global average pool over each (b, att-channel) plane
__global__ __launch_bounds__(256) void pool_kernel(const float* __restrict__ x,
                                                   float* __restrict__ pooled) {
    int bc = blockIdx.x;            // 0..255 = b*16 + c
    int b = bc >> 4, c = bc & 15;
    const float4* p = (const float4*)(x + ((size_t)(b*CIN + c)) * (HH*WW));
    float s = 0.f;
    #pragma unroll 4
    for (int i = threadIdx.x; i < (HH*WW/4); i += 256) {
        float4 v = p[i];
        s += (v.x + v.y) + (v.z + v.w);
    }
    #pragma unroll
    for (int off = 32; off > 0; off >>= 1) s += __shfl_down(s, off, 64);
    __shared__ float red[4];
    int lane = threadIdx.x & 63, wid = threadIdx.x >> 6;
    if (lane == 0) red[wid] = s;
    __syncthreads();
    if (threadIdx.x == 0)
        pooled[bc] = (red[0] + red[1] + red[2] + red[3]) * (1.0f/(HH*WW));
}

// ---------------- Kernel 2: tiny MLP -> dynamic 3x3 weights k[b][c][3][3]
__global__ __launch_bounds__(256) void mlp_kernel(const float* __restrict__ pooled,
                                                  const float* __restrict__ w1,
                                                  const float* __restrict__ b1,
                                                  const float* __restrict__ w2,
                                                  const float* __restrict__ b2,
                                                  float* __restrict__ kout) {
    __shared__ float h1[BB][HID];
    int t = threadIdx.x;
    if (t < BB*HID) {
        int b = t / HID, j = t % HID;
        float s = b1[j];
        #pragma unroll
        for (int a = 0; a < ATT; ++a) s += pooled[b*ATT + a] * w1[j*ATT + a];
        // exact GELU: x * 0.5 * (1 + erf(x/sqrt(2)))
        h1[b][j] = 0.5f * s * (1.0f + erff(s * 0.70710678118654752440f));
    }
    __syncthreads();
    for (int idx = t; idx < BB*ATT*SKK*SKK; idx += 256) {
        int b = idx / (ATT*SKK*SKK), o = idx % (ATT*SKK*SKK);
        float s = b2[o];
        #pragma unroll
        for (int a = 0; a < HID; ++a) s += h1[b][a] * w2[o*HID + a];
        kout[idx] = s;
    }
}

// ---------------- Kernel 3: transpose lk_filter OIHW -> [ci][i][j][co] (co contiguous)
__global__ __launch_bounds__(256) void tfilter_kernel(const float* __restrict__ lk,
                                                      float* __restrict__ wT) {
    int n = blockIdx.x * 256 + threadIdx.x;    // 0..43263, n = ((co*16+ci)*13+i)*13+j
    int j = n % LKK;
    int m = n / LKK;
    int i = m % LKK;  m /= LKK;
    int ci = m % ATT;
    int co = m / ATT;
    wT[(ci*(LKK*LKK) + i*LKK + j)*ATT + co] = lk[n];
}

// ---------------- Kernel 4: fused 13x13 conv + dynamic 3x3 + 1x1 fusion
__global__ __launch_bounds__(256, 2) void conv_fused_kernel(
    const float* __restrict__ x,     const float* __restrict__ wT,
    const float* __restrict__ kdyn,  const float* __restrict__ fw,
    const float* __restrict__ fb,    float* __restrict__ out)
{
    __shared__ float tile[ATT * TILE_H * TILE_W];   // 14080 floats = 56.3 KB
    const int b  = blockIdx.y;
    const int bx = blockIdx.x;            // 0..143
    const int tileX = bx % (WW/TW);       // 0..5
    const int tileY = bx / (WW/TW);       // 0..23
    const int h0 = tileY * TH, w0 = tileX * TW;
    const int tid = threadIdx.x;

    // ---- stage F_att tile (+halo, zero-padded) into LDS
    for (int idx = tid; idx < ATT*TILE_H*TILE_W; idx += 256) {
        int ci  = idx / (TILE_H*TILE_W);
        int rem = idx - ci*(TILE_H*TILE_W);
        int r   = rem / TILE_W;
        int c   = rem - r*TILE_W;
        int gh = h0 + r - HALO, gw = w0 + c - HALO;
        float v = 0.f;
        if ((unsigned)gh < HH && (unsigned)gw < WW)
            v = x[(((size_t)b*CIN + ci)*HH + gh)*WW + gw];
        tile[idx] = v;
    }
    __syncthreads();

    const int tx = tid & 31, ty = tid >> 5;   // pixel (h0+ty, w0+tx)

    float acc[ATT];
    #pragma unroll
    for (int c = 0; c < ATT; ++c) acc[c] = 0.f;

    // ---- 13x13 dense conv, 16ci -> 16co. Filter via wave-uniform scalar loads.
    for (int ci = 0; ci < ATT; ++ci) {
        const float* trow = &tile[ci*(TILE_H*TILE_W)];
        #pragma unroll 1
        for (int i = 0; i < LKK; ++i) {
            const float* r  = &trow[(ty + i)*TILE_W + tx];
            const float* wp = &wT[(ci*(LKK*LKK) + i*LKK)*ATT];
            #pragma unroll
            for (int j = 0; j < LKK; ++j) {
                float xv = r[j];                       // ds_read_b32, conflict-free
                #pragma unroll
                for (int co = 0; co < ATT; ++co)
                    acc[co] = fmaf(xv, wp[j*ATT + co], acc[co]);
            }
        }
    }

    // ---- dynamic 3x3 depthwise (weights per (b,c) from ws), added per channel
    const float* kb = &kdyn[b * ATT * 9];
    #pragma unroll
    for (int c = 0; c < ATT; ++c) {
        const float* tc = &tile[c*(TILE_H*TILE_W)];
        float d = 0.f;
        #pragma unroll
        for (int di = 0; di < 3; ++di)
            #pragma unroll
            for (int dj = 0; dj < 3; ++dj)
                d = fmaf(tc[(ty + HALO + di - 1)*TILE_W + (tx + HALO + dj - 1)],
                         kb[c*9 + di*3 + dj], d);
        acc[c] += d;
    }

    // ---- load identity channels for this pixel
    const int h = h0 + ty, w = w0 + tx;
    float idt[NIDT];
    #pragma unroll
    for (int c = 0; c < NIDT; ++c)
        idt[c] = x[(((size_t)b*CIN + (ATT + c))*HH + h)*WW + w];

    // ---- 1x1 fusion: out[o] = sum_c in[c] * fw[o][c] + fb[o]
    const size_t obase = ((size_t)b*CIN)*(HH*WW) + (size_t)h*WW + w;
    #pragma unroll 1
    for (int o = 0; o < CIN; ++o) {
        const float* fr = &fw[o*CIN];
        float s = fb[o];
        #pragma unroll
        for (int c = 0; c < ATT; ++c)  s = fmaf(acc[c], fr[c], s);
        #pragma unroll
        for (int c = 0; c < NIDT; ++c) s = fmaf(idt[c], fr[ATT + c], s);
        out[obase + (size_t)o*(HH*WW)] = s;
    }
}

extern "C" void kernel_launch(void* const* d_in, const int* in_sizes, int n_in,
                              void* d_out, int out_size, void* d_ws, size_t ws_size,
                              hipStream_t stream) {
    const float* x   = (const float*)d_in[0];
    const float* w1  = (const float*)d_in[1];
    const float* b1  = (const float*)d_in[2];
    const float* w2  = (const float*)d_in[3];
    const float* b2  = (const float*)d_in[4];
    const float* lk  = (const float*)d_in[5];
    const float* fw  = (const float*)d_in[6];
    const float* fb  = (const float*)d_in[7];
    float* out = (float*)d_out;

    // ws layout (floats): [0,256) pooled | [256,2560) kdyn | [2560,2560+43264) wT
    float* wsf    = (float*)d_ws;
    float* pooled = wsf;
    float* kdyn   = wsf + 256;
    float* wT     = wsf + 2560;

    pool_kernel<<<dim3(BB*ATT), dim3(256), 0, stream>>>(x, pooled);
    mlp_kernel<<<dim3(1), dim3(256), 0, stream>>>(pooled, w1, b1, w2, b2, kdyn);
    tfilter_kernel<<<dim3((ATT*ATT*LKK*LKK)/256), dim3(256), 0, stream>>>(lk, wT);
    conv_fused_kernel<<<dim3((WW/TW)*(HH/TH), BB), dim3(256), 0, stream>>>(
        x, wT, kdyn, fw, fb, out);
}

// Round 2
// 391.048 us; speedup vs baseline: 3.5606x; 3.5606x over previous
//
#include <hip/hip_runtime.h>
#include <math.h>

#define ATT 16
#define SKK 3
#define LKK 13
#define CIN 64
#define HID 8
#define BB 16
#define HH 192
#define WW 192
#define HW (HH*WW)            // 36864
#define NTAP 178              // 169 static taps + 9 dynamic (diag) taps
#define NPAIR 89              // NTAP/2 -> K=32 per MFMA

// conv pixel tile per block
#define TH 16
#define TW 32
#define TILE_H (TH+12)        // 28
#define TILE_W (TW+12)        // 44
#define TILE_PX (TILE_H*TILE_W)   // 1232
#define HSZ (TILE_PX*16)      // bytes per ci-half region: 19712

#define FSTRIDE 144           // fusion LDS row stride bytes (128 + 16 pad -> 2-way free)

typedef __attribute__((ext_vector_type(8))) short short8;
typedef __attribute__((ext_vector_type(4))) float f32x4;

__device__ inline unsigned short f2bf(float f) {   // round-to-nearest-even bf16
    unsigned u = __builtin_bit_cast(unsigned, f);
    unsigned r = u + 0x7FFFu + ((u >> 16) & 1u);
    return (unsigned short)(r >> 16);
}

// ---------------- Kernel 1: global average pool over each (b, att-channel) plane
__global__ __launch_bounds__(256) void pool_kernel(const float* __restrict__ x,
                                                   float* __restrict__ pooled) {
    int bc = blockIdx.x;            // b*16 + c
    int b = bc >> 4, c = bc & 15;
    const float4* p = (const float4*)(x + ((size_t)(b*CIN + c)) * HW);
    float s = 0.f;
    #pragma unroll 4
    for (int i = threadIdx.x; i < (HW/4); i += 256) {
        float4 v = p[i];
        s += (v.x + v.y) + (v.z + v.w);
    }
    #pragma unroll
    for (int off = 32; off > 0; off >>= 1) s += __shfl_down(s, off, 64);
    __shared__ float red[4];
    int lane = threadIdx.x & 63, wid = threadIdx.x >> 6;
    if (lane == 0) red[wid] = s;
    __syncthreads();
    if (threadIdx.x == 0)
        pooled[bc] = (red[0] + red[1] + red[2] + red[3]) * (1.0f/HW);
}

// ---------------- Kernel 2: tiny MLP -> dynamic 3x3 weights kdyn[b][c][9]
__global__ __launch_bounds__(256) void mlp_kernel(const float* __restrict__ pooled,
                                                  const float* __restrict__ w1,
                                                  const float* __restrict__ b1,
                                                  const float* __restrict__ w2,
                                                  const float* __restrict__ b2,
                                                  float* __restrict__ kout) {
    __shared__ float h1[BB][HID];
    int t = threadIdx.x;
    if (t < BB*HID) {
        int b = t / HID, j = t % HID;
        float s = b1[j];
        #pragma unroll
        for (int a = 0; a < ATT; ++a) s += pooled[b*ATT + a] * w1[j*ATT + a];
        h1[b][j] = 0.5f * s * (1.0f + erff(s * 0.70710678118654752440f));
    }
    __syncthreads();
    for (int idx = t; idx < BB*ATT*SKK*SKK; idx += 256) {
        int b = idx / (ATT*SKK*SKK), o = idx % (ATT*SKK*SKK);
        float s = b2[o];
        #pragma unroll
        for (int a = 0; a < HID; ++a) s += h1[b][a] * w2[o*HID + a];
        kout[idx] = s;
    }
}

// ---------------- Kernel 3: build MFMA B-operand tables (bf16)
// wB[b][t][co][ci]: t<169 -> lk_filter[co][ci][t/13][t%13]; t>=169 -> diag dyn 3x3
// fwBt[o][c] = bf16(fusion_w[o][c])
__global__ __launch_bounds__(256) void build_kernel(const float* __restrict__ lk,
                                                    const float* __restrict__ kdyn,
                                                    const float* __restrict__ fw,
                                                    unsigned short* __restrict__ wB,
                                                    unsigned short* __restrict__ fwBt) {
    int idx = blockIdx.x*256 + threadIdx.x;
    const int total = BB*NTAP*256;
    if (idx < total) {
        int b   = idx / (NTAP*256);
        int rem = idx % (NTAP*256);
        int t   = rem >> 8;
        int co  = (rem >> 4) & 15;
        int ci  = rem & 15;
        float v;
        if (t < 169) v = lk[(co*ATT + ci)*169 + t];
        else { int d = t - 169; v = (ci == co) ? kdyn[(b*ATT + ci)*9 + d] : 0.f; }
        wB[idx] = f2bf(v);
    } else {
        int j = idx - total;
        if (j < CIN*CIN) fwBt[j] = f2bf(fw[j]);
    }
}

// ---------------- Kernel 4: 13x13 conv + dyn 3x3, MFMA 16x16x32 bf16
// out: convres fp32 planar [b][16co][H][W]
__global__ __launch_bounds__(256, 3) void conv_mfma_kernel(const float* __restrict__ x,
                                                           const unsigned short* __restrict__ wB,
                                                           float* __restrict__ convres) {
    __shared__ char ldsA[2*HSZ];      // [ci-half][px][16B], 39424 B
    __shared__ int  lut[NTAP];        // tap -> byte offset in px*16 units
    const int b    = blockIdx.y;
    const int tile = blockIdx.x;                  // 0..71
    const int h0   = (tile / (WW/TW)) * TH;
    const int w0   = (tile % (WW/TW)) * TW;
    const int tid  = threadIdx.x;

    if (tid < NTAP) {
        int off;
        if (tid < 169) off = (tid/13)*TILE_W + (tid%13);
        else { int d = tid - 169; off = (5 + d/3)*TILE_W + (5 + d%3); }
        lut[tid] = off * 16;
    }

    // stage x_att tile (halo, zero-pad) fp32 -> bf16 pairs
    const float* xb = x + (size_t)b*CIN*HW;
    #pragma unroll
    for (int c4 = 0; c4 < 8; ++c4) {              // channel pair 2*c4, 2*c4+1
        const float* p0 = xb + (size_t)(2*c4)*HW;
        const float* p1 = p0 + HW;
        const int half = c4 >> 2, c2 = c4 & 3;
        for (int base = 0; base < TILE_PX; base += 256) {
            int px = base + tid;
            if (px < TILE_PX) {
                int tr = px / TILE_W, tc = px % TILE_W;
                int gh = h0 + tr - 6, gw = w0 + tc - 6;
                unsigned v = 0;
                if ((unsigned)gh < HH && (unsigned)gw < WW) {
                    int o = gh*WW + gw;
                    v = (unsigned)f2bf(p0[o]) | ((unsigned)f2bf(p1[o]) << 16);
                }
                *(unsigned*)&ldsA[half*HSZ + px*16 + c2*4] = v;
            }
        }
    }
    __syncthreads();

    const int lane = tid & 63, wv = tid >> 6;
    const int g = lane >> 4, r = lane & 15;
    const int halfoff = (g & 1) * HSZ;            // which 8-ci half this lane reads
    const int tl = g >> 1;                        // which tap of the pair

    int pixbase[8];
    #pragma unroll
    for (int mi = 0; mi < 8; ++mi) {
        int m = wv*8 + mi;                        // Mtile id 0..31
        int py = m >> 1, pxx = (m & 1) * 16;
        pixbase[mi] = (py*TILE_W + pxx + r) * 16 + halfoff;
    }

    const unsigned short* wbb = wB + (size_t)b*NTAP*256 + (lane & 15)*16 + (g & 1)*8;

    f32x4 acc[8];
    #pragma unroll
    for (int mi = 0; mi < 8; ++mi) acc[mi] = (f32x4){0.f,0.f,0.f,0.f};

    for (int pair = 0; pair < NPAIR; ++pair) {
        int t    = 2*pair + tl;
        int toff = lut[t];
        short8 bfrag = *(const short8*)&wbb[(size_t)t*256];
        #pragma unroll
        for (int mi = 0; mi < 8; ++mi) {
            short8 afrag = *(const short8*)&ldsA[pixbase[mi] + toff];
            acc[mi] = __builtin_amdgcn_mfma_f32_16x16x32_bf16(afrag, bfrag, acc[mi], 0, 0, 0);
        }
    }

    // store: D lane holds rows g*4+j (4 consecutive px), col = co = lane&15
    float* cr = convres + ((size_t)b*ATT + (lane & 15)) * HW;
    #pragma unroll
    for (int mi = 0; mi < 8; ++mi) {
        int m = wv*8 + mi;
        int py = m >> 1, pxx = (m & 1) * 16;
        *(f32x4*)&cr[(size_t)(h0 + py)*WW + w0 + pxx + g*4] = acc[mi];
    }
}

// ---------------- Kernel 5: 1x1 fusion (64->64) via MFMA, bias, store NCHW fp32
__global__ __launch_bounds__(256, 4) void fusion_kernel(const float* __restrict__ x,
                                                        const float* __restrict__ convres,
                                                        const unsigned short* __restrict__ fwBt,
                                                        const float* __restrict__ fb,
                                                        float* __restrict__ out) {
    __shared__ char fusA[256*FSTRIDE];            // [px][64ch bf16 + pad]
    const int b     = blockIdx.y;
    const int px0   = blockIdx.x * 256;
    const int tid   = threadIdx.x;

    // stage 64 channels x 256 px (16 from convres, 48 idt straight from x)
    #pragma unroll 4
    for (int c2 = 0; c2 < 32; ++c2) {
        int c = 2*c2;
        const float* p0 = (c < ATT) ? (convres + ((size_t)b*ATT + c)*HW)
                                    : (x + ((size_t)b*CIN + c)*HW);
        const float* p1 = p0 + HW;
        int o = px0 + tid;
        unsigned v = (unsigned)f2bf(p0[o]) | ((unsigned)f2bf(p1[o]) << 16);
        *(unsigned*)&fusA[tid*FSTRIDE + c2*4] = v;
    }
    __syncthreads();

    const int lane = tid & 63, wv = tid >> 6;
    const int g = lane >> 4, col = lane & 15;

    short8 bf[4][2];
    #pragma unroll
    for (int ot = 0; ot < 4; ++ot)
        #pragma unroll
        for (int kc = 0; kc < 2; ++kc)
            bf[ot][kc] = *(const short8*)&fwBt[(ot*16 + col)*CIN + kc*32 + g*8];

    #pragma unroll
    for (int mi = 0; mi < 4; ++mi) {
        int mpx = (wv*4 + mi) * 16;               // Mtile px base within chunk
        int apx = mpx + (lane & 15);
        short8 a0 = *(const short8*)&fusA[apx*FSTRIDE + (g*8)*2];
        short8 a1 = *(const short8*)&fusA[apx*FSTRIDE + (32 + g*8)*2];
        #pragma unroll
        for (int ot = 0; ot < 4; ++ot) {
            f32x4 acc = (f32x4){0.f,0.f,0.f,0.f};
            acc = __builtin_amdgcn_mfma_f32_16x16x32_bf16(a0, bf[ot][0], acc, 0, 0, 0);
            acc = __builtin_amdgcn_mfma_f32_16x16x32_bf16(a1, bf[ot][1], acc, 0, 0, 0);
            int o = ot*16 + col;
            f32x4 res = acc + fb[o];
            *(f32x4*)&out[((size_t)b*CIN + o)*HW + px0 + mpx + g*4] = res;
        }
    }
}

extern "C" void kernel_launch(void* const* d_in, const int* in_sizes, int n_in,
                              void* d_out, int out_size, void* d_ws, size_t ws_size,
                              hipStream_t stream) {
    const float* x   = (const float*)d_in[0];
    const float* w1  = (const float*)d_in[1];
    const float* b1  = (const float*)d_in[2];
    const float* w2  = (const float*)d_in[3];
    const float* b2  = (const float*)d_in[4];
    const float* lk  = (const float*)d_in[5];
    const float* fw  = (const float*)d_in[6];
    const float* fb  = (const float*)d_in[7];
    float* out = (float*)d_out;

    // ws layout (bytes)
    char* wsb = (char*)d_ws;
    float* pooled            = (float*)(wsb);                    // 256 f
    float* kdyn              = (float*)(wsb + 1024);             // 2304 f
    float* convres           = (float*)(wsb + 16384);            // 16*16*36864 f = 9.44 MB
    unsigned short* wB       = (unsigned short*)(wsb + 16384 + (size_t)BB*ATT*HW*4);
    unsigned short* fwBt     = (unsigned short*)((char*)wB + (size_t)BB*NTAP*256*2);

    pool_kernel<<<dim3(BB*ATT), dim3(256), 0, stream>>>(x, pooled);
    mlp_kernel<<<dim3(1), dim3(256), 0, stream>>>(pooled, w1, b1, w2, b2, kdyn);
    build_kernel<<<dim3((BB*NTAP*256 + CIN*CIN + 255)/256), dim3(256), 0, stream>>>(
        lk, kdyn, fw, wB, fwBt);
    conv_mfma_kernel<<<dim3((HH/TH)*(WW/TW), BB), dim3(256), 0, stream>>>(x, wB, convres);
    fusion_kernel<<<dim3(HW/256, BB), dim3(256), 0, stream>>>(x, convres, fwBt, fb, out);
}

// Round 3
// 347.012 us; speedup vs baseline: 4.0124x; 1.1269x over previous
//
#include <hip/hip_runtime.h>
#include <math.h>

#define ATT 16
#define SKK 3
#define LKK 13
#define CIN 64
#define HID 8
#define BB 16
#define HH 192
#define WW 192
#define HW (HH*WW)            // 36864
#define NTAP 170              // 169 taps (dyn 3x3 folded into center 3x3) + 1 zero pad
#define NPAIR 85              // NTAP/2 -> K=32 per MFMA

// conv pixel tile per block
#define TH 16
#define TW 32
#define TILE_H (TH+12)        // 28
#define TILE_W (TW+12)        // 44
#define TILE_PX (TILE_H*TILE_W)   // 1232
#define HSZ (TILE_PX*16)      // bytes per ci-half region: 19712

#define FSTRIDE 136           // fusion LDS row stride bytes (128 + 8 pad)
#define NIDT (CIN-ATT)        // 48

typedef __attribute__((ext_vector_type(8))) short short8;
typedef __attribute__((ext_vector_type(4))) float f32x4;

__device__ inline unsigned short f2bf(float f) {   // round-to-nearest-even bf16
    unsigned u = __builtin_bit_cast(unsigned, f);
    unsigned r = u + 0x7FFFu + ((u >> 16) & 1u);
    return (unsigned short)(r >> 16);
}

// ---------------- Kernel 1: global average pool over each (b, att-channel) plane
__global__ __launch_bounds__(256) void pool_kernel(const float* __restrict__ x,
                                                   float* __restrict__ pooled) {
    int bc = blockIdx.x;            // b*16 + c
    int b = bc >> 4, c = bc & 15;
    const float4* p = (const float4*)(x + ((size_t)(b*CIN + c)) * HW);
    float s = 0.f;
    #pragma unroll 4
    for (int i = threadIdx.x; i < (HW/4); i += 256) {
        float4 v = p[i];
        s += (v.x + v.y) + (v.z + v.w);
    }
    #pragma unroll
    for (int off = 32; off > 0; off >>= 1) s += __shfl_down(s, off, 64);
    __shared__ float red[4];
    int lane = threadIdx.x & 63, wid = threadIdx.x >> 6;
    if (lane == 0) red[wid] = s;
    __syncthreads();
    if (threadIdx.x == 0)
        pooled[bc] = (red[0] + red[1] + red[2] + red[3]) * (1.0f/HW);
}

// ---------------- Kernel 2: build all weight tables
// blocks [0, BB*NTAP): one (b, tap) each -> wB[b][t][co][ci] bf16,
//   with the dynamic 3x3 (from inlined MLP) folded into the center taps (diag ci==co).
// blocks [BB*NTAP, +16): fwBt[o][c] = bf16(fusion_w[o][c])
__global__ __launch_bounds__(256) void build_kernel(
    const float* __restrict__ lk, const float* __restrict__ pooled,
    const float* __restrict__ w1, const float* __restrict__ b1,
    const float* __restrict__ w2, const float* __restrict__ b2,
    const float* __restrict__ fw,
    unsigned short* __restrict__ wB, unsigned short* __restrict__ fwBt)
{
    int blk = blockIdx.x;
    if (blk < BB*NTAP) {
        int b = blk / NTAP, t = blk % NTAP;
        int co = threadIdx.x >> 4, ci = threadIdx.x & 15;
        float v = 0.f;
        if (t < 169) {
            v = lk[(co*ATT + ci)*169 + t];
            int ti = t / 13, tj = t % 13;
            if (ti >= 5 && ti <= 7 && tj >= 5 && tj <= 7 && ci == co) {
                // inline MLP for this (b, ci, dyn-tap)
                float h[HID];
                #pragma unroll
                for (int a = 0; a < HID; ++a) {
                    float s = b1[a];
                    #pragma unroll
                    for (int q = 0; q < ATT; ++q) s += pooled[b*ATT + q] * w1[a*ATT + q];
                    h[a] = 0.5f * s * (1.0f + erff(s * 0.70710678118654752440f));
                }
                int o = ci*9 + (ti-5)*3 + (tj-5);
                float s = b2[o];
                #pragma unroll
                for (int a = 0; a < HID; ++a) s += h[a] * w2[o*HID + a];
                v += s;
            }
        }
        wB[((size_t)b*NTAP + t)*256 + co*16 + ci] = f2bf(v);
    } else {
        int idx = (blk - BB*NTAP)*256 + threadIdx.x;   // 4096 elems
        fwBt[idx] = f2bf(fw[idx]);
    }
}

// ---------------- Kernel 3: fused 13x13 conv (+folded dyn 3x3) + 1x1 fusion + bias
__global__ __launch_bounds__(256, 3) void conv_fused_kernel(
    const float* __restrict__ x, const unsigned short* __restrict__ wB,
    const unsigned short* __restrict__ fwBt, const float* __restrict__ fb,
    float* __restrict__ out)
{
    __shared__ char ldsA[2*HSZ];      // 39424 B; fusion phase reuses [0, 34816)
    __shared__ int  lut[NTAP];
    const int b    = blockIdx.y;
    const int tile = blockIdx.x;
    const int h0   = (tile / (WW/TW)) * TH;
    const int w0   = (tile % (WW/TW)) * TW;
    const int tid  = threadIdx.x;

    if (tid < NTAP) lut[tid] = (tid < 169) ? ((tid/13)*TILE_W + (tid%13))*16 : 0;

    // ---- stage x_att tile (halo, zero-pad) fp32 -> bf16 pairs: [half][px][16B]
    const float* xb = x + (size_t)b*CIN*HW;
    #pragma unroll
    for (int c4 = 0; c4 < 8; ++c4) {
        const float* p0 = xb + (size_t)(2*c4)*HW;
        const float* p1 = p0 + HW;
        const int half = c4 >> 2, c2 = c4 & 3;
        for (int base = 0; base < TILE_PX; base += 256) {
            int px = base + tid;
            if (px < TILE_PX) {
                int tr = px / TILE_W, tc = px % TILE_W;
                int gh = h0 + tr - 6, gw = w0 + tc - 6;
                unsigned v = 0;
                if ((unsigned)gh < HH && (unsigned)gw < WW) {
                    int o = gh*WW + gw;
                    v = (unsigned)f2bf(p0[o]) | ((unsigned)f2bf(p1[o]) << 16);
                }
                *(unsigned*)&ldsA[half*HSZ + px*16 + c2*4] = v;
            }
        }
    }
    __syncthreads();

    const int lane = tid & 63, wv = tid >> 6;
    const int g = lane >> 4, r = lane & 15;
    const int halfoff = (g & 1) * HSZ;
    const int tl = g >> 1;

    int pixbase[8];
    #pragma unroll
    for (int mi = 0; mi < 8; ++mi) {
        int m = wv*8 + mi;
        int py = m >> 1, pxx = (m & 1) * 16;
        pixbase[mi] = (py*TILE_W + pxx + r) * 16 + halfoff;
    }

    const unsigned short* wbb = wB + (size_t)b*NTAP*256 + r*16 + (g & 1)*8;

    f32x4 acc[8];
    #pragma unroll
    for (int mi = 0; mi < 8; ++mi) acc[mi] = (f32x4){0.f,0.f,0.f,0.f};

    // ---- software-pipelined pair loop (prefetch next B-frag + lut)
    int tcur = tl;
    short8 bcur = *(const short8*)&wbb[(size_t)tcur*256];
    int ocur = lut[tcur];
    for (int pair = 0; pair < NPAIR-1; ++pair) {
        int tn = 2*(pair+1) + tl;
        short8 bn = *(const short8*)&wbb[(size_t)tn*256];
        int on = lut[tn];
        #pragma unroll
        for (int mi = 0; mi < 8; ++mi) {
            short8 af = *(const short8*)&ldsA[pixbase[mi] + ocur];
            acc[mi] = __builtin_amdgcn_mfma_f32_16x16x32_bf16(af, bcur, acc[mi], 0, 0, 0);
        }
        bcur = bn; ocur = on;
    }
    #pragma unroll
    for (int mi = 0; mi < 8; ++mi) {
        short8 af = *(const short8*)&ldsA[pixbase[mi] + ocur];
        acc[mi] = __builtin_amdgcn_mfma_f32_16x16x32_bf16(af, bcur, acc[mi], 0, 0, 0);
    }

    // ---- fusion epilogue: two 256-px chunks, LDS [px][64ch bf16] stride FSTRIDE
    short8 bfw[4][2];
    #pragma unroll
    for (int ot = 0; ot < 4; ++ot)
        #pragma unroll
        for (int kc = 0; kc < 2; ++kc)
            bfw[ot][kc] = *(const short8*)&fwBt[(ot*16 + r)*CIN + kc*32 + g*8];
    float fbv[4];
    #pragma unroll
    for (int ot = 0; ot < 4; ++ot) fbv[ot] = fb[ot*16 + r];

    const int prow = tid >> 5, pcol = tid & 31;
    for (int ck = 0; ck < 2; ++ck) {
        __syncthreads();   // conv reads (or prev chunk MFMAs) done before overwrite
        // stage 48 identity channels straight from x
        size_t gbase = ((size_t)b*CIN + ATT)*HW + (size_t)(h0 + ck*8 + prow)*WW + w0 + pcol;
        #pragma unroll 4
        for (int c2 = 0; c2 < 24; ++c2) {
            float v0 = x[gbase + (size_t)(2*c2)*HW];
            float v1 = x[gbase + (size_t)(2*c2+1)*HW];
            *(unsigned*)&ldsA[tid*FSTRIDE + 32 + c2*4] =
                (unsigned)f2bf(v0) | ((unsigned)f2bf(v1) << 16);
        }
        // stage 16 conv channels from acc (transpose: D col=co,row=px -> [px][co])
        if ((wv >> 1) == ck) {
            #pragma unroll
            for (int mi = 0; mi < 8; ++mi) {
                int m = wv*8 + mi, py = m >> 1, pxx = (m & 1)*16;
                int pl0 = (py - ck*8)*32 + pxx + g*4;
                #pragma unroll
                for (int j = 0; j < 4; ++j)
                    *(unsigned short*)&ldsA[(pl0 + j)*FSTRIDE + r*2] = f2bf(acc[mi][j]);
            }
        }
        __syncthreads();
        // 1x1 fusion: 4 M-tiles/wave x 4 N-tiles x (K=64 -> 2 MFMA)
        #pragma unroll
        for (int q = 0; q < 4; ++q) {
            int mt = wv*4 + q;
            int arow = mt*16 + r;
            short8 a0 = *(const short8*)&ldsA[arow*FSTRIDE + g*16];
            short8 a1 = *(const short8*)&ldsA[arow*FSTRIDE + 64 + g*16];
            #pragma unroll
            for (int ot = 0; ot < 4; ++ot) {
                f32x4 ac = (f32x4){0.f,0.f,0.f,0.f};
                ac = __builtin_amdgcn_mfma_f32_16x16x32_bf16(a0, bfw[ot][0], ac, 0, 0, 0);
                ac = __builtin_amdgcn_mfma_f32_16x16x32_bf16(a1, bfw[ot][1], ac, 0, 0, 0);
                ac = ac + fbv[ot];
                int row = ck*8 + (mt >> 1), col = (mt & 1)*16 + g*4;
                *(f32x4*)&out[((size_t)b*CIN + ot*16 + r)*HW
                              + (size_t)(h0 + row)*WW + w0 + col] = ac;
            }
        }
    }
}

extern "C" void kernel_launch(void* const* d_in, const int* in_sizes, int n_in,
                              void* d_out, int out_size, void* d_ws, size_t ws_size,
                              hipStream_t stream) {
    const float* x   = (const float*)d_in[0];
    const float* w1  = (const float*)d_in[1];
    const float* b1  = (const float*)d_in[2];
    const float* w2  = (const float*)d_in[3];
    const float* b2  = (const float*)d_in[4];
    const float* lk  = (const float*)d_in[5];
    const float* fw  = (const float*)d_in[6];
    const float* fb  = (const float*)d_in[7];
    float* out = (float*)d_out;

    // ws layout (bytes): pooled @0 (1KB) | wB @1024 (16*170*256*2 = 1392640) | fwBt
    char* wsb = (char*)d_ws;
    float* pooled        = (float*)(wsb);
    unsigned short* wB   = (unsigned short*)(wsb + 1024);
    unsigned short* fwBt = (unsigned short*)(wsb + 1024 + (size_t)BB*NTAP*256*2);

    pool_kernel<<<dim3(BB*ATT), dim3(256), 0, stream>>>(x, pooled);
    build_kernel<<<dim3(BB*NTAP + 16), dim3(256), 0, stream>>>(
        lk, pooled, w1, b1, w2, b2, fw, wB, fwBt);
    conv_fused_kernel<<<dim3((HH/TH)*(WW/TW), BB), dim3(256), 0, stream>>>(
        x, wB, fwBt, fb, out);
}